// Round 7
// baseline (466.237 us; speedup 1.0000x reference)
//
#include <hip/hip_runtime.h>
#include <hip/hip_bf16.h>

typedef __hip_bfloat16 bf16;
typedef __attribute__((ext_vector_type(8))) short short8;
typedef __attribute__((ext_vector_type(4))) float f32x4;

#define QL   2048
#define KLEN 2048
#define BATCH 2
#define EMB  1024
#define NH   16
#define HD   64
#define SPE  4095   // 2*KLEN - 1 pe rows (slice starts at pe row 1)
#define NEG_INF (-1.0e30f)

// ---------------------------------------------------------------------------
__device__ int detect_f32(const void* __restrict__ p) {
    const unsigned short* u = (const unsigned short*)p;
    int bad = 0;
    for (int i = 0; i < 256; i++) {
        int e = (u[i] >> 7) & 0xFF;
        if (e >= 0x8A) bad++;   // |x| >= 2048, or NaN/Inf
    }
    return bad >= 8;
}

__device__ __forceinline__ ushort4 cvt4(const void* src, long u4i, int f32) {
    ushort4 o;
    if (f32) {
        float4 v = ((const float4*)src)[u4i];
        bf16 a = (bf16)v.x, b = (bf16)v.y, c = (bf16)v.z, e = (bf16)v.w;
        o.x = *(unsigned short*)&a; o.y = *(unsigned short*)&b;
        o.z = *(unsigned short*)&c; o.w = *(unsigned short*)&e;
    } else {
        o = ((const ushort4*)src)[u4i];
    }
    return o;
}

// fused weight/bias conversion: 5 x 1M weights + cb + pb -> dst slab
__global__ __launch_bounds__(256) void conv_w(
    const void* w0, const void* w1, const void* w2, const void* w3, const void* w4,
    const void* cb, const void* pb, bf16* __restrict__ dst)
{
    const int t = threadIdx.x;
    const int bid = blockIdx.x;
    __shared__ int f32s;
    if (bid < 1280) {
        const int seg = bid >> 8, inner = bid & 255;
        const void* src = seg == 0 ? w0 : seg == 1 ? w1 : seg == 2 ? w2 : seg == 3 ? w3 : w4;
        bf16* d = dst + (size_t)seg * 1048576;
        if (t == 0) f32s = detect_f32(src);
        __syncthreads();
        const int f32 = f32s;
#pragma unroll
        for (int i = 0; i < 4; i++) {
            long u4i = (long)inner * 1024 + i * 256 + t;
            ((ushort4*)d)[u4i] = cvt4(src, u4i, f32);
        }
    } else {
        if (t == 0) f32s = detect_f32(cb);
        __syncthreads();
        const int f32 = f32s;
        ((ushort4*)(dst + 5242880))[t]        = cvt4(cb, t, f32);
        ((ushort4*)(dst + 5242880 + 1024))[t] = cvt4(pb, t, f32);
    }
}

// fused activation conversion: query/key/value/pe -> 4 bf16 slabs
__global__ __launch_bounds__(256) void conv_act(
    const void* q, const void* k, const void* v, const void* pe,
    bf16* __restrict__ dq, bf16* __restrict__ dk,
    bf16* __restrict__ dv, bf16* __restrict__ dp)
{
    const int t = threadIdx.x;
    const int seg = blockIdx.x >> 10, inner = blockIdx.x & 1023;
    const void* src = seg == 0 ? q : seg == 1 ? k : seg == 2 ? v : pe;
    bf16* d = seg == 0 ? dq : seg == 1 ? dk : seg == 2 ? dv : dp;
    const long srcOff4 = (seg == 3) ? 256 : 0;               // pe: skip row 0
    const long zero4   = (seg == 3) ? 1048320 : (1L << 40);  // pe: zero row 4095
    __shared__ int f32s;
    if (t == 0) f32s = detect_f32(src);
    __syncthreads();
    const int f32 = f32s;
#pragma unroll
    for (int i = 0; i < 4; i++) {
        long u4i = (long)inner * 1024 + i * 256 + t;
        ushort4 o;
        if (u4i >= zero4) { o.x = o.y = o.z = o.w = 0; }
        else o = cvt4(src, srcOff4 + u4i, f32);
        ((ushort4*)d)[u4i] = o;
    }
}

// ---------------------------------------------------------------------------
__device__ __forceinline__ void llds16(const bf16* g, bf16* l) {
    __builtin_amdgcn_global_load_lds(
        (const __attribute__((address_space(1))) void*)g,
        (__attribute__((address_space(3))) void*)l,
        16, 0, 0);
}

// ---------------------------------------------------------------------------
// Unified MFMA GEMM: C[4096,1024] = A @ W^T, 128x128 tiles, BK=32.
// mode 0: q proj -> qc,qp (+biases); 1: k; 2: v; 3: pe (Mwr 4095); 4: out f32
// ---------------------------------------------------------------------------
struct GArgs {
    const bf16* A[5]; const bf16* W[5];
    bf16 *qc, *qp, *kw, *vw, *kpos;
    float* outf;
    const bf16 *cb, *pb;
};

__global__ __launch_bounds__(256) void gemm_all(GArgs g, int zbase)
{
    const int mode = zbase + blockIdx.z;
    const bf16* __restrict__ A = g.A[mode];
    const bf16* __restrict__ W = g.W[mode];

    __shared__ __align__(16) bf16 Asd[128 * 32];
    __shared__ __align__(16) bf16 Wsd[128 * 32];

    const int t = threadIdx.x;
    const int w = t >> 6, lane = t & 63, lm = lane & 15, quad = lane >> 4;
    const int m0 = blockIdx.x * 128, n0 = blockIdx.y * 128;
    const int wm = (w & 1) * 64, wn = (w >> 1) * 64;
    const int rswz = (quad ^ ((lm >> 1) & 3)) * 8;

    f32x4 acc[4][4] = {};

    for (int k0 = 0; k0 < 1024; k0 += 32) {
#pragma unroll
        for (int i = 0; i < 2; i++) {
            int c = i * 256 + t, r = c >> 2, gc = (c & 3) ^ ((r >> 1) & 3);
            llds16(A + (size_t)(m0 + r) * 1024 + k0 + gc * 8, Asd + (size_t)(c & ~63) * 8);
        }
#pragma unroll
        for (int i = 0; i < 2; i++) {
            int c = i * 256 + t, r = c >> 2, gc = (c & 3) ^ ((r >> 1) & 3);
            llds16(W + (size_t)(n0 + r) * 1024 + k0 + gc * 8, Wsd + (size_t)(c & ~63) * 8);
        }
        __syncthreads();

        short8 wf[4];
#pragma unroll
        for (int nt = 0; nt < 4; nt++)
            wf[nt] = *(const short8*)&Wsd[(wn + nt * 16 + lm) * 32 + rswz];
#pragma unroll
        for (int mt = 0; mt < 4; mt++) {
            short8 af = *(const short8*)&Asd[(wm + mt * 16 + lm) * 32 + rswz];
#pragma unroll
            for (int nt = 0; nt < 4; nt++)
                acc[mt][nt] = __builtin_amdgcn_mfma_f32_16x16x32_bf16(af, wf[nt], acc[mt][nt], 0, 0, 0);
        }
        __syncthreads();
    }

    const int Mwr = (mode == 3) ? 4095 : 4096;
#pragma unroll
    for (int mt = 0; mt < 4; mt++)
#pragma unroll
    for (int nt = 0; nt < 4; nt++)
#pragma unroll
    for (int r4 = 0; r4 < 4; r4++) {
        int row = m0 + wm + mt * 16 + quad * 4 + r4;
        int col = n0 + wn + nt * 16 + lm;
        if (row >= Mwr) continue;
        float v = acc[mt][nt][r4];
        if (mode == 0) {
            int l = row >> 1, bb = row & 1, hh = col >> 6, d = col & 63;
            size_t idx = ((size_t)(bb * NH + hh) * QL + l) * HD + d;
            g.qc[idx] = (bf16)(v + __bfloat162float(g.cb[col]));
            g.qp[idx] = (bf16)(v + __bfloat162float(g.pb[col]));
        } else if (mode == 1 || mode == 2) {
            int l = row >> 1, bb = row & 1, hh = col >> 6, d = col & 63;
            size_t idx = ((size_t)(bb * NH + hh) * KLEN + l) * HD + d;
            (mode == 1 ? g.kw : g.vw)[idx] = (bf16)v;
        } else if (mode == 3) {
            int hh = col >> 6, d = col & 63;
            g.kpos[((size_t)hh * SPE + row) * HD + d] = (bf16)v;
        } else {
            g.outf[(size_t)row * 1024 + col] = v;
        }
    }
}

// ---------------------------------------------------------------------------
// attn v3: q-tile 64, 4 waves (each owns 16 q-rows), 1 barrier/iter.
// Scores + pos band in register C-layout; TXL shift via ds_bpermute;
// softmax wave-local (width-16 shuffles); P through per-wave Pb region;
// K/Kp double-buffered DMA prefetch; V double-buffered transposed.
// ---------------------------------------------------------------------------
__global__ __launch_bounds__(256) void attn_v3(
    const bf16* __restrict__ qc_g, const bf16* __restrict__ qp_g,
    const bf16* __restrict__ k_g,  const bf16* __restrict__ v_g,
    const bf16* __restrict__ kpos_g, bf16* __restrict__ ao)
{
    const int bx = 31 - blockIdx.x;   // heavy-first
    const int q0 = bx * 64;
    const int h = blockIdx.y, b = blockIdx.z;

    const bf16* qc_bh  = qc_g + ((size_t)(b * NH + h) * QL) * HD;
    const bf16* qp_bh  = qp_g + ((size_t)(b * NH + h) * QL) * HD;
    const bf16* k_bh   = k_g  + ((size_t)(b * NH + h) * KLEN) * HD;
    const bf16* v_bh   = v_g  + ((size_t)(b * NH + h) * KLEN) * HD;
    const bf16* kpos_h = kpos_g + (size_t)h * SPE * HD;

    __shared__ __align__(16) bf16 K_s [2][64 * 64];
    __shared__ __align__(16) bf16 Kp_s[2][128 * 64];
    __shared__ __align__(16) bf16 Vt_s[2][64 * 64];
    __shared__ __align__(16) bf16 Pb_s[64 * 72];

    const int t = threadIdx.x;
    const int w = t >> 6, lane = t & 63, lm = lane & 15, quad = lane >> 4;
    const int woff = 48 - w * 16;     // wave band offset into staged Kp rows

    const int vrr = t >> 3, vch = t & 7;
    const int vslot = (vrr >> 2) ^ vch, voff = (2 * vrr) & 7;

    // Q fragments in registers (whole kernel)
    short8 qcf[2], qpf[2];
    {
        const size_t qr = (size_t)(q0 + w * 16 + lm) * HD;
        qcf[0] = *(const short8*)&qc_bh[qr + quad * 8];
        qcf[1] = *(const short8*)&qc_bh[qr + 32 + quad * 8];
        qpf[0] = *(const short8*)&qp_bh[qr + quad * 8];
        qpf[1] = *(const short8*)&qp_bh[qr + 32 + quad * 8];
    }

    float m_run[4], l_run[4];
    f32x4 accO[4] = {};
#pragma unroll
    for (int r = 0; r < 4; r++) { m_run[r] = NEG_INF; l_run[r] = 0.0f; }

    const int nkt = bx + 1;

    // prologue: stage tile 0 into buf 0
#pragma unroll
    for (int i = 0; i < 2; i++) {
        int c = i * 256 + t, r = c >> 3, ch = c & 7, gc = ch ^ (r & 7);
        llds16(k_bh + (size_t)r * HD + gc * 8, &K_s[0][(c & ~63) * 8]);
    }
    {
        const int sU = 1984 - q0;   // >= 0 (q0 <= 1984)
#pragma unroll
        for (int i = 0; i < 4; i++) {
            int c = i * 256 + t, r = c >> 3, ch = c & 7, gc = ch ^ (r & 7);
            llds16(kpos_h + (size_t)(sU + r) * HD + gc * 8, &Kp_s[0][(c & ~63) * 8]);
        }
    }
    short8 vv0 = *(const short8*)&v_bh[(size_t)(2 * vrr) * HD + vch * 8];
    short8 vv1 = *(const short8*)&v_bh[(size_t)(2 * vrr + 1) * HD + vch * 8];

    for (int kt = 0; kt < nkt; kt++) {
        const int k0 = kt * 64;
        const int buf = kt & 1;

        // transpose-write V tile kt (u32 pairs, 2-way conflicts = free)
#pragma unroll
        for (int j = 0; j < 8; j++) {
            unsigned int pair = (unsigned int)(unsigned short)vv0[j]
                              | ((unsigned int)(unsigned short)vv1[j] << 16);
            *(unsigned int*)&Vt_s[buf][(vch * 8 + j) * 64 + vslot * 8 + voff] = pair;
        }
        __syncthreads();   // THE barrier: drains kt's DMA, publishes Vt[buf]

        // prefetch kt+1 right after the barrier -> full-iter latency window
        if (kt + 1 < nkt) {
            const int k0n = k0 + 64;
            const int nb = 1 - buf;
#pragma unroll
            for (int i = 0; i < 2; i++) {
                int c = i * 256 + t, r = c >> 3, ch = c & 7, gc = ch ^ (r & 7);
                llds16(k_bh + (size_t)(k0n + r) * HD + gc * 8, &K_s[nb][(c & ~63) * 8]);
            }
            const int sUn = k0n - q0 + 1984;
#pragma unroll
            for (int i = 0; i < 4; i++) {
                int c = i * 256 + t, r = c >> 3, ch = c & 7, gc = ch ^ (r & 7);
                llds16(kpos_h + (size_t)(sUn + r) * HD + gc * 8, &Kp_s[nb][(c & ~63) * 8]);
            }
            vv0 = *(const short8*)&v_bh[(size_t)(k0n + 2 * vrr) * HD + vch * 8];
            vv1 = *(const short8*)&v_bh[(size_t)(k0n + 2 * vrr + 1) * HD + vch * 8];
        }

        // content scores S[16x64] (register C-layout)
        f32x4 S[4];
#pragma unroll
        for (int n = 0; n < 4; n++) {
            int rowB = n * 16 + lm;
            short8 b0 = *(const short8*)&K_s[buf][rowB * 64 + ((quad)     ^ (rowB & 7)) * 8];
            short8 b1 = *(const short8*)&K_s[buf][rowB * 64 + ((4 + quad) ^ (rowB & 7)) * 8];
            f32x4 a = {0, 0, 0, 0};
            a = __builtin_amdgcn_mfma_f32_16x16x32_bf16(qcf[0], b0, a, 0, 0, 0);
            a = __builtin_amdgcn_mfma_f32_16x16x32_bf16(qcf[1], b1, a, 0, 0, 0);
            S[n] = a;
        }
        // pos band Bd[16x80] (wave-local window)
        f32x4 Bd[5];
#pragma unroll
        for (int bt = 0; bt < 5; bt++) {
            int rS = bt * 16 + lm + woff;
            short8 b0 = *(const short8*)&Kp_s[buf][rS * 64 + ((quad)     ^ (rS & 7)) * 8];
            short8 b1 = *(const short8*)&Kp_s[buf][rS * 64 + ((4 + quad) ^ (rS & 7)) * 8];
            f32x4 a = {0, 0, 0, 0};
            a = __builtin_amdgcn_mfma_f32_16x16x32_bf16(qpf[0], b0, a, 0, 0, 0);
            a = __builtin_amdgcn_mfma_f32_16x16x32_bf16(qpf[1], b1, a, 0, 0, 0);
            Bd[bt] = a;
        }

        // diagonal shift via bpermute + mask + wave-local online softmax
        float p[4][4];
        float aReg[4];
#pragma unroll
        for (int reg = 0; reg < 4; reg++) {
            const int rr = quad * 4 + reg;
            const int off = 15 + lm - rr;                 // 0..30
            const int idxb = (quad * 16 + (off & 15)) << 2;
            const bool hi = (off & 16) != 0;
#pragma unroll
            for (int n = 0; n < 4; n++) {
                float lo = __int_as_float(__builtin_amdgcn_ds_bpermute(idxb, __float_as_int(Bd[n][reg])));
                float hv = __int_as_float(__builtin_amdgcn_ds_bpermute(idxb, __float_as_int(Bd[n + 1][reg])));
                float pos = hi ? hv : lo;
                float s = (S[n][reg] + pos) * 0.125f;
                if (k0 + n * 16 + lm > q0 + w * 16 + rr) s = NEG_INF;
                p[n][reg] = s;
            }
            float mx = fmaxf(fmaxf(p[0][reg], p[1][reg]), fmaxf(p[2][reg], p[3][reg]));
            mx = fmaxf(mx, __shfl_xor(mx, 1, 16));
            mx = fmaxf(mx, __shfl_xor(mx, 2, 16));
            mx = fmaxf(mx, __shfl_xor(mx, 4, 16));
            mx = fmaxf(mx, __shfl_xor(mx, 8, 16));
            float mnew = fmaxf(m_run[reg], mx);
            float alpha = __expf(m_run[reg] - mnew);
            m_run[reg] = mnew;
            float ls = 0.0f;
#pragma unroll
            for (int n = 0; n < 4; n++) { p[n][reg] = __expf(p[n][reg] - mnew); ls += p[n][reg]; }
            ls += __shfl_xor(ls, 1, 16);
            ls += __shfl_xor(ls, 2, 16);
            ls += __shfl_xor(ls, 4, 16);
            ls += __shfl_xor(ls, 8, 16);
            l_run[reg] = l_run[reg] * alpha + ls;
            aReg[reg] = alpha;
        }

        // P -> bf16 into per-wave Pb region (wave-local: no barrier)
#pragma unroll
        for (int n = 0; n < 4; n++)
#pragma unroll
            for (int reg = 0; reg < 4; reg++)
                Pb_s[(w * 16 + quad * 4 + reg) * 72 + n * 16 + lm] = (bf16)p[n][reg];

        // O update: acc = alpha*acc + P V
        {
            short8 a0 = *(const short8*)&Pb_s[(w * 16 + lm) * 72 + quad * 8];
            short8 a1 = *(const short8*)&Pb_s[(w * 16 + lm) * 72 + 32 + quad * 8];
#pragma unroll
            for (int n = 0; n < 4; n++) {
                int d = n * 16 + lm, dc = d >> 3;
                short8 b0 = *(const short8*)&Vt_s[buf][d * 64 + ((quad)     ^ dc) * 8];
                short8 b1 = *(const short8*)&Vt_s[buf][d * 64 + ((4 + quad) ^ dc) * 8];
#pragma unroll
                for (int reg = 0; reg < 4; reg++) accO[n][reg] *= aReg[reg];
                accO[n] = __builtin_amdgcn_mfma_f32_16x16x32_bf16(a0, b0, accO[n], 0, 0, 0);
                accO[n] = __builtin_amdgcn_mfma_f32_16x16x32_bf16(a1, b1, accO[n], 0, 0, 0);
            }
        }
    }

    float linv[4];
#pragma unroll
    for (int reg = 0; reg < 4; reg++) linv[reg] = 1.0f / l_run[reg];
#pragma unroll
    for (int n = 0; n < 4; n++)
#pragma unroll
        for (int reg = 0; reg < 4; reg++) {
            int row = q0 + w * 16 + quad * 4 + reg;
            ao[((size_t)row * BATCH + b) * EMB + h * HD + n * 16 + lm] =
                (bf16)(accO[n][reg] * linv[reg]);
        }
}

// ---------------------------------------------------------------------------
extern "C" void kernel_launch(void* const* d_in, const int* in_sizes, int n_in,
                              void* d_out, int out_size, void* d_ws, size_t ws_size,
                              hipStream_t stream)
{
    const void* query = d_in[0];
    const void* key   = d_in[1];
    const void* value = d_in[2];
    const void* pe    = d_in[3];
    const void* w_q   = d_in[4];
    const void* w_k   = d_in[5];
    const void* w_v   = d_in[6];
    const void* w_kp  = d_in[7];
    const void* w_out = d_in[8];
    const void* cb    = d_in[9];
    const void* pb    = d_in[10];
    float* out = (float*)d_out;

    const size_t SLAB = 4194304;
    bf16* qc   = (bf16*)d_ws;          // S0
    bf16* qp   = qc + SLAB;            // S1
    bf16* kw   = qp + SLAB;            // S2
    bf16* vw   = kw + SLAB;            // S3
    bf16* kpos = vw + SLAB;            // S4
    bf16* ao   = kpos + SLAB;          // S5 (pe staging before GEMMs; attn out after)
    bf16* stgK = ao + SLAB;            // S6 (key staging)
    bf16* wqb  = stgK + SLAB;          // S7: wq,wk,wv,wkp,wo,cb,pb
    bf16* wkb  = wqb + 1048576;
    bf16* wvb  = wkb + 1048576;
    bf16* wkpb = wvb + 1048576;
    bf16* wob  = wkpb + 1048576;
    bf16* cbb  = wob + 1048576;
    bf16* pbb  = cbb + 1024;

    bf16* stgQ = (bf16*)d_out;              // query staging (d_out 1st half)
    bf16* stgV = (bf16*)d_out + SLAB;       // value staging (d_out 2nd half)

    dim3 blk(256);

    conv_w<<<dim3(1281), blk, 0, stream>>>(w_q, w_k, w_v, w_kp, w_out, cb, pb, wqb);
    conv_act<<<dim3(4096), blk, 0, stream>>>(query, key, value, pe, stgQ, stgK, stgV, ao);

    GArgs g;
    g.A[0] = stgQ; g.A[1] = stgK; g.A[2] = stgV; g.A[3] = ao; g.A[4] = ao;
    g.W[0] = wqb;  g.W[1] = wkb;  g.W[2] = wvb;  g.W[3] = wkpb; g.W[4] = wob;
    g.qc = qc; g.qp = qp; g.kw = kw; g.vw = vw; g.kpos = kpos;
    g.outf = out; g.cb = cbb; g.pb = pbb;

    gemm_all<<<dim3(32, 8, 4), blk, 0, stream>>>(g, 0);   // q,k,v,pe projections

    attn_v3<<<dim3(32, NH, BATCH), blk, 0, stream>>>(qc, qp, kw, vw, kpos, ao);

    gemm_all<<<dim3(32, 8, 1), blk, 0, stream>>>(g, 4);   // output projection
}